// Round 15
// baseline (701.664 us; speedup 1.0000x reference)
//
#include <hip/hip_runtime.h>

#define BDIM 512

typedef float f32x4 __attribute__((ext_vector_type(4)));
typedef short bf16x8 __attribute__((ext_vector_type(8)));

#define MFMA(a, b, c) __builtin_amdgcn_mfma_f32_16x16x32_bf16((a), (b), (c), 0, 0, 0)

// ---- weight workspace layout (bf16 elements in d_ws) ----
constexpr int OQ1 = 0;                  // qW1t [256][32]  (k 20..31 = 0)
constexpr int OK1w = 8192;              // kW1t [256][32]
constexpr int OV1 = 16384;              // vW1t [256][32]
constexpr int OQ2 = 24576;              // G2t = (qW2 @ kW2^T)^T [256][256] (g2_prep)
constexpr int OK2w = 90112;             // kW2t: DEAD (K-L2 fused into Q~)
constexpr int OV2 = 155648;             // f32 pb1_adj[256] @ +0; f32 qb2t[256] @ +256 f32
constexpr int OP1 = 221184;             // [256][512]: cols 0..255 = G4t = (qW2@pW1q)^T;
                                        // cols 256..511 = G3t = (vW2@pW1c)^T
constexpr int OP2 = 352256;             // pW2t [32][256]  (rows 24..31 = 0)
constexpr int WTOT = 360448;            // elements (720896 bytes)

// ---- LDS layout (bytes) ---- (identical to R12/R14 champion)
// Hc arena [144][256] spans SP+HT2+KVT (83968..157696). Phases that READ Hc
// (Q~-GEMM, p-L1 halves, p-L2) must not concurrently write HT2/KVT.
// K-loop: HT2/KVT ping-pong Hk chunks [32][256] (compile-time per phase).
// V-loop: HT2/KVT ping-pong Hv^T bufs [256][32] (compile-time per phase).
constexpr int OFF_Q   = 0;              // Qs: Q~ (scores), then Hq (p-L1)
constexpr int OFF_XS  = 73728;
constexpr int OFF_SP  = 83968;          // 43808 bytes incl. masked-read slack
constexpr int OFF_HT2 = 127776;
constexpr int OFF_KVT = 144160;
constexpr int OFF_RWL = 160544;
constexpr int SMEM_BYTES = 161120;

constexpr int SPS = 152;                // SP row stride (elements)

__device__ __forceinline__ unsigned short f2b(float f) {
  unsigned int u = __float_as_uint(f);
  return (unsigned short)((u + 0x7fffu + ((u >> 16) & 1u)) >> 16);
}
__device__ __forceinline__ float bfu(unsigned short u) {
  return __uint_as_float(((unsigned int)u) << 16);
}

// plain fragment load: lane l -> row rb+(l&15), k-cols kb+(l>>4)*8
__device__ __forceinline__ bf16x8 frag(const unsigned short* m, int rb, int stride,
                                       int kb, int lane) {
  return *(const bf16x8*)(m + (rb + (lane & 15)) * stride + kb + ((lane >> 4) << 3));
}
// swizzled fragment loads (LDS)
__device__ __forceinline__ bf16x8 frag256s(const unsigned short* m, int rb, int kb, int lane) {
  const int row = rb + (lane & 15);
  const int c = (kb + ((lane >> 4) << 3)) ^ ((row & 7) << 3);
  return *(const bf16x8*)(m + row * 256 + c);
}
__device__ __forceinline__ bf16x8 frag32s(const unsigned short* m, int rb, int lane) {
  const int row = rb + (lane & 15);
  const int c = ((lane >> 4) << 3) ^ (((row >> 1) & 3) << 3);
  return *(const bf16x8*)(m + row * 32 + c);
}
// swizzled scalar-store index helpers (must match the frag*s formulas)
__device__ __forceinline__ int swz256(int r, int c) { return r * 256 + (c ^ ((r & 7) << 3)); }
__device__ __forceinline__ int swz32 (int r, int c) { return r * 32  + (c ^ (((r >> 1) & 3) << 3)); }

// ---------------- weight prep: f32 -> bf16, transposed, padded ----------------
__global__ void prep_w(const float* __restrict__ qW1, const float* __restrict__ qW2,
                       const float* __restrict__ kW1, const float* __restrict__ kW2,
                       const float* __restrict__ vW1, const float* __restrict__ vW2,
                       const float* __restrict__ pW1, const float* __restrict__ pW2,
                       unsigned short* __restrict__ ws) {
  int i = blockIdx.x * 256 + threadIdx.x;
  if (i >= WTOT) return;
  float v = 0.f;
  if (i < OQ2) {
    int sel = i >> 13, r = i & 8191;
    int o = r >> 5, k = r & 31;
    const float* W = (sel == 0) ? qW1 : (sel == 1) ? kW1 : vW1;
    if (k < 20) v = W[k * 256 + o];
  } else if (i < OP1) {
    int r = i - OQ2;
    int sel = r >> 16, q = r & 65535;
    int o = q >> 8, k = q & 255;
    const float* W = (sel == 0) ? qW2 : (sel == 1) ? kW2 : vW2;
    v = W[k * 256 + o];                  // OQ2 / OP1 overwritten by g*_prep below
  } else if (i < OP2) {
    int r = i - OP1;
    int o = r >> 9, f = r & 511;
    v = pW1[f * 256 + o];
  } else {
    int r = i - OP2;
    int o = r >> 8, k = r & 255;
    if (o < 24) v = pW2[k * 24 + o];
  }
  ws[i] = f2b(v);
}

// ---- G3t = (vW2 @ pW1c)^T into OP1 ctx half; pb1_adj = pb1 + vb2@pW1c ----
__global__ void g3_prep(const float* __restrict__ vW2, const float* __restrict__ pW1,
                        const float* __restrict__ pb1, const float* __restrict__ vb2,
                        unsigned short* __restrict__ ws) {
  __shared__ float col[256];
  __shared__ float red[256];
  const int o = blockIdx.x, c = threadIdx.x;
  col[c] = pW1[(256 + c) * 256 + o];
  __syncthreads();
  float acc = 0.f;
#pragma unroll 4
  for (int h = 0; h < 256; ++h) acc += vW2[c * 256 + h] * col[h];
  ws[OP1 + o * 512 + 256 + c] = f2b(acc);
  red[c] = vb2[c] * col[c];
  __syncthreads();
  for (int st = 128; st > 0; st >>= 1) {
    if (c < st) red[c] += red[c + st];
    __syncthreads();
  }
  if (c == 0) ((float*)(ws + OV2))[o] = pb1[o] + red[0];
}

// ---- G2t[h][g] = dot(qW2 row g, kW2 row h) into OQ2; qb2t[h] = qb2·kW2[h] ----
__global__ void g2_prep(const float* __restrict__ qW2, const float* __restrict__ kW2,
                        const float* __restrict__ qb2, unsigned short* __restrict__ ws) {
  __shared__ float krow[256];
  __shared__ float red[256];
  const int h = blockIdx.x, g = threadIdx.x;
  krow[g] = kW2[h * 256 + g];
  __syncthreads();
  float acc = 0.f;
#pragma unroll 4
  for (int o = 0; o < 256; ++o) acc += qW2[g * 256 + o] * krow[o];
  ws[OQ2 + h * 256 + g] = f2b(acc);
  red[g] = qb2[g] * krow[g];
  __syncthreads();
  for (int st = 128; st > 0; st >>= 1) {
    if (g < st) red[g] += red[g + st];
    __syncthreads();
  }
  if (g == 0) ((float*)(ws + OV2))[256 + h] = red[0];
}

// ---- G4t[n][k] = Σ_o qW2[k][o]·pW1[o][n] into OP1 Q half; pb1_adj += qb2@pW1q ----
__global__ void g4_prep(const float* __restrict__ qW2, const float* __restrict__ pW1,
                        const float* __restrict__ qb2, unsigned short* __restrict__ ws) {
  __shared__ float col[256];
  __shared__ float red[256];
  const int n = blockIdx.x, k = threadIdx.x;
  col[k] = pW1[k * 256 + n];
  __syncthreads();
  float acc = 0.f;
#pragma unroll 4
  for (int o = 0; o < 256; ++o) acc += qW2[k * 256 + o] * col[o];
  ws[OP1 + n * 512 + k] = f2b(acc);
  red[k] = qb2[k] * col[k];
  __syncthreads();
  for (int st = 128; st > 0; st >>= 1) {
    if (k < st) red[k] += red[k + st];
    __syncthreads();
  }
  if (k == 0) ((float*)(ws + OV2))[n] += red[0];
}

// ---------------- fused main kernel: 1 block = 1 batch, 8 waves ----------------
__global__ __launch_bounds__(BDIM) __attribute__((amdgpu_waves_per_eu(2, 2)))
void motion_mfma(const float* __restrict__ x,
                 const float* __restrict__ qb1v,
                 const float* __restrict__ kb1v,
                 const float* __restrict__ vb1v,
                 const float* __restrict__ pb2v,
                 const unsigned short* __restrict__ ws,
                 float* __restrict__ out) {
  extern __shared__ char smem[];
  unsigned short* Qs  = (unsigned short*)(smem + OFF_Q);
  unsigned short* XS  = (unsigned short*)(smem + OFF_XS);
  unsigned short* SP  = (unsigned short*)(smem + OFF_SP);
  unsigned short* Hc  = (unsigned short*)(smem + OFF_SP);   // Hq / PHn / hp arena
  unsigned short* HT2 = (unsigned short*)(smem + OFF_HT2);
  unsigned short* KVT = (unsigned short*)(smem + OFF_KVT);
  float* RWL = (float*)(smem + OFF_RWL);
  float* Ob  = (float*)(smem + 0);
  float* MT  = (float*)(smem + 14400);

  const int tid = threadIdx.x, lane = tid & 63, w = tid >> 6;
  const int l15 = lane & 15, rs = ((lane >> 4) << 2);
  const int cb = w * 32;               // wave's two 16-col n-tiles
  const int b = blockIdx.x;
  const f32x4 zf4 = {0.f, 0.f, 0.f, 0.f};
  const bf16x8 zb8 = {0, 0, 0, 0, 0, 0, 0, 0};

  // P0: stage x -> XS [160][32] bf16 (swizzled32), zero-padded; nontemporal reads
  const float* xb = x + (size_t)b * 2700;
  for (int i = tid; i < 160 * 32; i += BDIM) {
    int r = i >> 5, c = i & 31;
    float v = (r < 135 && c < 20) ? __builtin_nontemporal_load(xb + r * 20 + c) : 0.f;
    XS[swz32(r, c)] = f2b(v);
  }

  // hoisted L1 weight fragments + biases (reused across chunks)
  const bf16x8 qw0 = frag(ws + OQ1, cb, 32, 0, lane);
  const bf16x8 qw1 = frag(ws + OQ1, cb + 16, 32, 0, lane);
  const bf16x8 kw0 = frag(ws + OK1w, cb, 32, 0, lane);
  const bf16x8 kw1 = frag(ws + OK1w, cb + 16, 32, 0, lane);
  const bf16x8 vw0 = frag(ws + OV1, cb, 32, 0, lane);
  const bf16x8 vw1 = frag(ws + OV1, cb + 16, 32, 0, lane);
  const float qbb0 = qb1v[cb + l15], qbb1 = qb1v[cb + 16 + l15];
  const float kbb0 = kb1v[cb + l15], kbb1 = kb1v[cb + 16 + l15];
  const float vbb0 = vb1v[cb + l15], vbb1 = vb1v[cb + 16 + l15];
  __syncthreads();

  // L1: relu(XS-chunk(s0) @ kW1 + kb1) -> buf [32][256] (swz256); buf is a
  // compile-time constant at every call site (no pointer arrays — R13 lesson)
  auto L1 = [&](int s0, unsigned short* buf) {
#pragma unroll
    for (int mm = 0; mm < 2; ++mm) {
      bf16x8 a = frag32s(XS, s0 + mm * 16, lane);
      f32x4 c0 = MFMA(a, kw0, zf4), c1 = MFMA(a, kw1, zf4);
#pragma unroll
      for (int r = 0; r < 4; ++r) {
        buf[swz256(mm * 16 + rs + r, cb + l15)]      = f2b(fmaxf(c0[r] + kbb0, 0.f));
        buf[swz256(mm * 16 + rs + r, cb + 16 + l15)] = f2b(fmaxf(c1[r] + kbb1, 0.f));
      }
    }
  };
  // L1T: relu(XS-chunk(s0) @ vW1 + vb1) -> buf [256][32] TRANSPOSED (swz32)
  auto L1T = [&](int s0, unsigned short* buf) {
#pragma unroll
    for (int mm = 0; mm < 2; ++mm) {
      bf16x8 a = frag32s(XS, s0 + mm * 16, lane);
      f32x4 c0 = MFMA(a, vw0, zf4), c1 = MFMA(a, vw1, zf4);
#pragma unroll
      for (int r = 0; r < 4; ++r) {
        int tok = mm * 16 + rs + r;
        buf[swz32(cb + l15,      tok)] = f2b(fmaxf(c0[r] + vbb0, 0.f));
        buf[swz32(cb + 16 + l15, tok)] = f2b(fmaxf(c1[r] + vbb1, 0.f));
      }
    }
  };
  // Q-L1 into full [144][256] (Hq); used twice (XS stays resident)
  auto QL1full = [&](unsigned short* dst) {
#pragma unroll
    for (int m = 0; m < 9; ++m) {
      bf16x8 a = frag32s(XS, m * 16, lane);
      f32x4 c0 = MFMA(a, qw0, zf4);
      f32x4 c1 = MFMA(a, qw1, zf4);
#pragma unroll
      for (int r = 0; r < 4; ++r) {
        dst[swz256(m * 16 + rs + r, cb + l15)]      = f2b(fmaxf(c0[r] + qbb0, 0.f));
        dst[swz256(m * 16 + rs + r, cb + 16 + l15)] = f2b(fmaxf(c1[r] + qbb1, 0.f));
      }
    }
  };
  // scores slab: S[:, s0..s0+31] = Q~ @ Hk^T / 16 (kb2 cancels in softmax);
  // kbuf compile-time per call site
  auto SCORES = [&](int s0, const unsigned short* kbuf) {
#pragma unroll
    for (int rep = 0; rep < 3; ++rep) {
      int j = w + rep * 8;
      if (j < 18) {
        int m = j >> 1, n = j & 1;
        int sb = s0 + n * 16;
        if (sb < 144) {
          f32x4 sa = zf4;
#pragma unroll
          for (int ks = 0; ks < 8; ++ks) {
            bf16x8 qa = frag256s(Qs, m * 16, ks * 32, lane);
            bf16x8 kf = frag256s(kbuf, n * 16, ks * 32, lane);
            sa = MFMA(qa, kf, sa);
          }
#pragma unroll
          for (int r = 0; r < 4; ++r)
            SP[(m * 16 + rs + r) * SPS + sb + l15] = f2b(sa[r] * 0.0625f);
        }
      }
    }
  };

  // ---------------- Q-L1: Hq -> arena ----------------
  QL1full(Hc);
  __syncthreads();

  // ---------------- Q~ = Hq @ G2 + qb2t -> Qs (reads ALL of Hc) ----------------
  {
    const float* qb2t = ((const float*)(ws + OV2)) + 256;
    f32x4 acc[9][2];
#pragma unroll
    for (int m = 0; m < 9; ++m) { acc[m][0] = zf4; acc[m][1] = zf4; }
#pragma unroll
    for (int ks = 0; ks < 8; ++ks) {
      bf16x8 g0 = frag(ws + OQ2, cb, 256, ks * 32, lane);
      bf16x8 g1 = frag(ws + OQ2, cb + 16, 256, ks * 32, lane);
#pragma unroll
      for (int m = 0; m < 9; ++m) {
        bf16x8 a = frag256s(Hc, m * 16, ks * 32, lane);
        acc[m][0] = MFMA(a, g0, acc[m][0]);
        acc[m][1] = MFMA(a, g1, acc[m][1]);
      }
    }
    float bb20 = qb2t[cb + l15], bb21 = qb2t[cb + 16 + l15];
#pragma unroll
    for (int m = 0; m < 9; ++m)
#pragma unroll
      for (int r = 0; r < 4; ++r) {
        Qs[swz256(m * 16 + rs + r, cb + l15)]      = f2b(acc[m][0][r] + bb20);
        Qs[swz256(m * 16 + rs + r, cb + 16 + l15)] = f2b(acc[m][1][r] + bb21);
      }
  }
  __syncthreads();   // Hq reads complete before HT2 (aliasing arena) is written

  // ---------------- K-L1(0) -> HT2 ----------------
  L1(0, HT2);
  __syncthreads();

  // ---------------- K phases, fully unrolled: [K-L1(next) + scores(cur)] bar ----
  // Hk ping-pong HT2/KVT with compile-time buffers; scores reads the PREVIOUS
  // phase's buffer while K-L1 writes the other (disjoint 16KB regions).
  L1(32, KVT);  SCORES(0, HT2);   __syncthreads();
  L1(64, HT2);  SCORES(32, KVT);  __syncthreads();
  L1(96, KVT);  SCORES(64, HT2);  __syncthreads();
  L1(128, HT2); SCORES(96, KVT);  __syncthreads();
  L1T(0, KVT);  SCORES(128, HT2); __syncthreads();   // first Hv^T chunk -> KVT

  // ---------------- softmax in-place (mask s>=135), denom -> RWL ----------------
#pragma unroll
  for (int pass = 0; pass < 2; ++pass) {
    int r = pass * 128 + (tid >> 2);
    if (r < 144) {
      int j = tid & 3;
      float mx = -1e30f;
      for (int s = j; s < 135; s += 4) mx = fmaxf(mx, bfu(SP[r * SPS + s]));
      mx = fmaxf(mx, __shfl_xor(mx, 1));
      mx = fmaxf(mx, __shfl_xor(mx, 2));
      float sum = 0.f;
      for (int s = j; s < 135; s += 4) {
        float p = __expf(bfu(SP[r * SPS + s]) - mx);
        SP[r * SPS + s] = f2b(p);
        sum += p;
      }
      sum += __shfl_xor(sum, 1);
      sum += __shfl_xor(sum, 2);
      if (j == 0) RWL[r] = sum;
      for (int s = 135 + j; s < 144; s += 4) SP[r * SPS + s] = 0;
    }
  }
  __syncthreads();

  // ---------------- V phases (fused): PH += P @ Hv; Hv(0) already in KVT ------
  f32x4 ctx[9][2];
#pragma unroll
  for (int m = 0; m < 9; ++m) { ctx[m][0] = zf4; ctx[m][1] = zf4; }
  auto PV = [&](int s0, const unsigned short* vbuf, bool maskch) {
    bf16x8 v0 = frag32s(vbuf, cb, lane);
    bf16x8 v1 = frag32s(vbuf, cb + 16, lane);
    const bool mask = maskch && (lane >= 32);   // token slots >= 144
#pragma unroll
    for (int m = 0; m < 9; ++m) {
      bf16x8 pa = frag(SP, m * 16, SPS, s0, lane);
      if (mask) pa = zb8;
      ctx[m][0] = MFMA(pa, v0, ctx[m][0]);
      ctx[m][1] = MFMA(pa, v1, ctx[m][1]);
    }
  };
  L1T(32, HT2);  PV(0, KVT, false);  __syncthreads();
  L1T(64, KVT);  PV(32, HT2, false); __syncthreads();
  L1T(96, HT2);  PV(64, KVT, false); __syncthreads();
  L1T(128, KVT); PV(96, HT2, false); __syncthreads();
                 PV(128, KVT, true); __syncthreads();

  // normalize PHn -> Hc arena  AND  recompute Hq -> Qs (disjoint; one phase)
#pragma unroll
  for (int m = 0; m < 9; ++m)
#pragma unroll
    for (int r = 0; r < 4; ++r) {
      int t = m * 16 + rs + r;
      float inv = 1.0f / RWL[t];
      Hc[swz256(t, cb + l15)]      = f2b(ctx[m][0][r] * inv);
      Hc[swz256(t, cb + 16 + l15)] = f2b(ctx[m][1][r] * inv);
    }
  QL1full(Qs);                         // Q~ dead; Qs := Hq again (XS resident)
  __syncthreads();

  // ---------------- p-L1: hp = relu(Hq @ G4 + PHn @ G3 + pb1_adj) --------------
  {
    const float* pb1adj = (const float*)(ws + OV2);
    float pbias0 = pb1adj[cb + l15], pbias1 = pb1adj[cb + 16 + l15];
    f32x4 pacc[9][2];
#pragma unroll
    for (int m = 0; m < 9; ++m) {
      pacc[m][0] = (f32x4){pbias0, pbias0, pbias0, pbias0};
      pacc[m][1] = (f32x4){pbias1, pbias1, pbias1, pbias1};
    }
#pragma unroll
    for (int ks = 0; ks < 8; ++ks) {        // Hq half (fused G4t)
      bf16x8 g0 = frag(ws + OP1, cb, 512, ks * 32, lane);
      bf16x8 g1 = frag(ws + OP1, cb + 16, 512, ks * 32, lane);
#pragma unroll
      for (int m = 0; m < 9; ++m) {
        bf16x8 a = frag256s(Qs, m * 16, ks * 32, lane);
        pacc[m][0] = MFMA(a, g0, pacc[m][0]);
        pacc[m][1] = MFMA(a, g1, pacc[m][1]);
      }
    }
#pragma unroll
    for (int ks = 0; ks < 8; ++ks) {        // PHn half (fused G3t)
      bf16x8 g0 = frag(ws + OP1, cb, 512, 256 + ks * 32, lane);
      bf16x8 g1 = frag(ws + OP1, cb + 16, 512, 256 + ks * 32, lane);
#pragma unroll
      for (int m = 0; m < 9; ++m) {
        bf16x8 a = frag256s(Hc, m * 16, ks * 32, lane);
        pacc[m][0] = MFMA(a, g0, pacc[m][0]);
        pacc[m][1] = MFMA(a, g1, pacc[m][1]);
      }
    }
    __syncthreads();   // Hq/PHn reads done by ALL waves before hp/MT overwrite
#pragma unroll
    for (int m = 0; m < 9; ++m)
#pragma unroll
      for (int r = 0; r < 4; ++r) {
        Hc[swz256(m * 16 + rs + r, cb + l15)]      = f2b(fmaxf(pacc[m][0][r], 0.f));
        Hc[swz256(m * 16 + rs + r, cb + 16 + l15)] = f2b(fmaxf(pacc[m][1][r], 0.f));
      }
  }
  // IDCT basis into MT (Qs region dead)
  for (int i = tid; i < 576; i += BDIM) {
    int kk = i / 24, t = i - kk * 24;
    float c = (kk == 0) ? 0.20412414523193150f : 0.28867513459481287f;
    MT[i] = c * cosf(0.065449846949787352f * (float)(kk * (2 * t + 1)));
  }
  __syncthreads();

  // ---------------- p-L2: o = hp @ pW2 + pb2 -> Ob [144][25] f32 ----------------
#pragma unroll
  for (int rep = 0; rep < 3; ++rep) {
    int j = w + rep * 8;
    if (j < 18) {
      int m = j >> 1, n = j & 1;
      f32x4 oa = zf4;
#pragma unroll
      for (int ks = 0; ks < 8; ++ks) {
        bf16x8 a = frag256s(Hc, m * 16, ks * 32, lane);
        bf16x8 g = frag(ws + OP2, n * 16, 256, ks * 32, lane);
        oa = MFMA(a, g, oa);
      }
      int c = n * 16 + l15;
      if (c < 24) {
        float bb = pb2v[c];
#pragma unroll
        for (int r = 0; r < 4; ++r)
          Ob[(m * 16 + rs + r) * 25 + c] = oa[r] + bb;
      }
    }
  }
  __syncthreads();

  // ---------------- IDCT + coalesced nontemporal store ----------------
  for (int i = tid; i < 3240; i += BDIM) {
    int tt = i / 135, tok = i - tt * 135;
    float a = 0.f;
#pragma unroll
    for (int k = 0; k < 24; ++k)
      a = fmaf(Ob[tok * 25 + k], MT[k * 24 + tt], a);
    __builtin_nontemporal_store(a, out + (size_t)b * 3240 + i);
  }
}

extern "C" void kernel_launch(void* const* d_in, const int* in_sizes, int n_in,
                              void* d_out, int out_size, void* d_ws, size_t ws_size,
                              hipStream_t stream) {
  (void)in_sizes; (void)n_in; (void)out_size;
  if (ws_size < (size_t)WTOT * 2) return;

  const float* x   = (const float*)d_in[0];
  const float* qW1 = (const float*)d_in[1];
  const float* qb1 = (const float*)d_in[2];
  const float* qW2 = (const float*)d_in[3];
  const float* qb2 = (const float*)d_in[4];
  const float* kW1 = (const float*)d_in[5];
  const float* kb1 = (const float*)d_in[6];
  const float* kW2 = (const float*)d_in[7];
  const float* vW1 = (const float*)d_in[9];
  const float* vb1 = (const float*)d_in[10];
  const float* vW2 = (const float*)d_in[11];
  const float* vb2 = (const float*)d_in[12];
  const float* pW1 = (const float*)d_in[13];
  const float* pb1 = (const float*)d_in[14];
  const float* pW2 = (const float*)d_in[15];
  const float* pb2 = (const float*)d_in[16];
  float* out = (float*)d_out;
  unsigned short* ws = (unsigned short*)d_ws;

  prep_w<<<dim3((WTOT + 255) / 256), dim3(256), 0, stream>>>(
      qW1, qW2, kW1, kW2, vW1, vW2, pW1, pW2, ws);
  g3_prep<<<dim3(256), dim3(256), 0, stream>>>(vW2, pW1, pb1, vb2, ws);
  g2_prep<<<dim3(256), dim3(256), 0, stream>>>(qW2, kW2, qb2, ws);
  g4_prep<<<dim3(256), dim3(256), 0, stream>>>(qW2, pW1, qb2, ws);   // after g3

  (void)hipFuncSetAttribute((const void*)motion_mfma,
                            hipFuncAttributeMaxDynamicSharedMemorySize, SMEM_BYTES);
  motion_mfma<<<dim3(2048), dim3(BDIM), SMEM_BYTES, stream>>>(
      x, qb1, kb1, vb1, pb2, ws, out);
}

// Round 16
// 556.184 us; speedup vs baseline: 1.2616x; 1.2616x over previous
//
#include <hip/hip_runtime.h>

#define BDIM 512

typedef float f32x4 __attribute__((ext_vector_type(4)));
typedef short bf16x8 __attribute__((ext_vector_type(8)));

#define MFMA(a, b, c) __builtin_amdgcn_mfma_f32_16x16x32_bf16((a), (b), (c), 0, 0, 0)

// ---- weight workspace layout (bf16 elements in d_ws) ----
constexpr int OQ1 = 0;                  // qW1t [256][32]  (k 20..31 = 0)
constexpr int OK1w = 8192;              // kW1t [256][32]
constexpr int OV1 = 16384;              // vW1t [256][32]
constexpr int OQ2 = 24576;              // qW2t [256][256]
constexpr int OK2w = 90112;             // kW2t [256][256]
constexpr int OV2 = 155648;             // f32 pb1_adj[256] @ +0; f32 pb2M[24] @ +256 (floats)
constexpr int OP1 = 221184;             // [256][512]: cols 0..255 = pW1t Q-half;
                                        // cols 256..511 = G3t = (vW2 @ pW1c)^T  (g3_prep)
constexpr int OP2 = 352256;             // pW2Mt [32][256] = (pW2@M)^T (g5_prep; rows 24..31 = 0)
constexpr int WTOT = 360448;            // elements (720896 bytes)

// ---- LDS layout (bytes) ---- (identical to champion R12/R14)
constexpr int OFF_Q   = 0;
constexpr int OFF_XS  = 73728;
constexpr int OFF_SP  = 83968;          // 43808 bytes incl. masked-read slack
constexpr int OFF_HT2 = 127776;
constexpr int OFF_KVT = 144160;
constexpr int OFF_RWL = 160544;
constexpr int SMEM_BYTES = 161120;

constexpr int SPS = 152;                // SP row stride (elements)

__device__ __forceinline__ unsigned short f2b(float f) {
  unsigned int u = __float_as_uint(f);
  return (unsigned short)((u + 0x7fffu + ((u >> 16) & 1u)) >> 16);
}
__device__ __forceinline__ float bfu(unsigned short u) {
  return __uint_as_float(((unsigned int)u) << 16);
}

// plain fragment load: lane l -> row rb+(l&15), k-cols kb+(l>>4)*8
__device__ __forceinline__ bf16x8 frag(const unsigned short* m, int rb, int stride,
                                       int kb, int lane) {
  return *(const bf16x8*)(m + (rb + (lane & 15)) * stride + kb + ((lane >> 4) << 3));
}
// swizzled fragment loads (LDS)
__device__ __forceinline__ bf16x8 frag256s(const unsigned short* m, int rb, int kb, int lane) {
  const int row = rb + (lane & 15);
  const int c = (kb + ((lane >> 4) << 3)) ^ ((row & 7) << 3);
  return *(const bf16x8*)(m + row * 256 + c);
}
__device__ __forceinline__ bf16x8 frag32s(const unsigned short* m, int rb, int lane) {
  const int row = rb + (lane & 15);
  const int c = ((lane >> 4) << 3) ^ (((row >> 1) & 3) << 3);
  return *(const bf16x8*)(m + row * 32 + c);
}
// swizzled scalar-store index helpers (must match the frag*s formulas)
__device__ __forceinline__ int swz256(int r, int c) { return r * 256 + (c ^ ((r & 7) << 3)); }
__device__ __forceinline__ int swz32 (int r, int c) { return r * 32  + (c ^ (((r >> 1) & 3) << 3)); }

// ---------------- weight prep: f32 -> bf16, transposed, padded ----------------
__global__ void prep_w(const float* __restrict__ qW1, const float* __restrict__ qW2,
                       const float* __restrict__ kW1, const float* __restrict__ kW2,
                       const float* __restrict__ vW1, const float* __restrict__ vW2,
                       const float* __restrict__ pW1, const float* __restrict__ pW2,
                       unsigned short* __restrict__ ws) {
  int i = blockIdx.x * 256 + threadIdx.x;
  if (i >= WTOT) return;
  float v = 0.f;
  if (i < OQ2) {
    int sel = i >> 13, r = i & 8191;
    int o = r >> 5, k = r & 31;
    const float* W = (sel == 0) ? qW1 : (sel == 1) ? kW1 : vW1;
    if (k < 20) v = W[k * 256 + o];
  } else if (i < OP1) {
    int r = i - OQ2;
    int sel = r >> 16, q = r & 65535;
    int o = q >> 8, k = q & 255;
    const float* W = (sel == 0) ? qW2 : (sel == 1) ? kW2 : vW2;
    v = W[k * 256 + o];
  } else if (i < OP2) {
    int r = i - OP1;
    int o = r >> 9, f = r & 511;
    v = pW1[f * 256 + o];                // ctx half overwritten by g3_prep later
  } else {
    int r = i - OP2;
    int o = r >> 8, k = r & 255;
    if (o < 24) v = pW2[k * 24 + o];     // rows 0..23 overwritten by g5_prep later
  }
  ws[i] = f2b(v);
}

// ---------------- fused-weight prep: G3t = (vW2 @ pW1c)^T; pb1_adj ----------------
__global__ void g3_prep(const float* __restrict__ vW2, const float* __restrict__ pW1,
                        const float* __restrict__ pb1, const float* __restrict__ vb2,
                        unsigned short* __restrict__ ws) {
  __shared__ float col[256];             // pW1[256+h][o], h = 0..255
  __shared__ float red[256];
  const int o = blockIdx.x, c = threadIdx.x;
  col[c] = pW1[(256 + c) * 256 + o];
  __syncthreads();
  float acc = 0.f;
#pragma unroll 4
  for (int h = 0; h < 256; ++h) acc += vW2[c * 256 + h] * col[h];
  ws[OP1 + o * 512 + 256 + c] = f2b(acc);          // G3t[o][c] into OP1 ctx slot
  red[c] = vb2[c] * col[c];
  __syncthreads();
  for (int st = 128; st > 0; st >>= 1) {
    if (c < st) red[c] += red[c + st];
    __syncthreads();
  }
  if (c == 0) ((float*)(ws + OV2))[o] = pb1[o] + red[0];   // pb1_adj[o]
}

// ---- g5: fold IDCT into p-L2 weights: pW2Mt[t][h] = Σ_k pW2[h][k]·M[k][t];
//          pb2M[t] = Σ_k pb2[k]·M[k][t].  M = ortho IDCT-II basis.
__global__ void g5_prep(const float* __restrict__ pW2, const float* __restrict__ pb2,
                        unsigned short* __restrict__ ws) {
  const int t = blockIdx.x;              // 0..23
  const int h = threadIdx.x;             // 0..255
  float acc = 0.f;
#pragma unroll
  for (int k = 0; k < 24; ++k) {
    float c = (k == 0) ? 0.20412414523193150f : 0.28867513459481287f;
    float m = c * cosf(0.065449846949787352f * (float)(k * (2 * t + 1)));
    acc += pW2[h * 24 + k] * m;
  }
  ws[OP2 + t * 256 + h] = f2b(acc);
  if (h == 0) {
    float s = 0.f;
#pragma unroll
    for (int k = 0; k < 24; ++k) {
      float c = (k == 0) ? 0.20412414523193150f : 0.28867513459481287f;
      s += pb2[k] * c * cosf(0.065449846949787352f * (float)(k * (2 * t + 1)));
    }
    ((float*)(ws + OV2))[256 + t] = s;   // pb2M[t]
  }
}

// ---------------- fused main kernel: 1 block = 1 batch, 8 waves ----------------
__global__ __launch_bounds__(BDIM) __attribute__((amdgpu_waves_per_eu(2, 2)))
void motion_mfma(const float* __restrict__ x,
                 const float* __restrict__ qb1v, const float* __restrict__ qb2v,
                 const float* __restrict__ kb1v, const float* __restrict__ kb2v,
                 const float* __restrict__ vb1v, const float* __restrict__ vb2v,
                 const unsigned short* __restrict__ ws,
                 float* __restrict__ out) {
  extern __shared__ char smem[];
  unsigned short* Qs  = (unsigned short*)(smem + OFF_Q);
  unsigned short* XS  = (unsigned short*)(smem + OFF_XS);
  unsigned short* SP  = (unsigned short*)(smem + OFF_SP);
  unsigned short* Hc  = (unsigned short*)(smem + OFF_SP);   // H / PHn / hp arena
  unsigned short* HT2 = (unsigned short*)(smem + OFF_HT2);
  unsigned short* KVT = (unsigned short*)(smem + OFF_KVT);
  unsigned short* VB0 = (unsigned short*)(smem + OFF_HT2);  // Hv^T buf A [256][32]
  unsigned short* VB1 = (unsigned short*)(smem + OFF_KVT);  // Hv^T buf B [256][32]
  float* RWL = (float*)(smem + OFF_RWL);
  float* Ob  = (float*)(smem + 0);      // [144][25] f32 over dead Qs

  const int tid = threadIdx.x, lane = tid & 63, w = tid >> 6;
  const int l15 = lane & 15, rs = ((lane >> 4) << 2);
  const int cb = w * 32;               // wave's two 16-col n-tiles
  const int b = blockIdx.x;
  const f32x4 zf4 = {0.f, 0.f, 0.f, 0.f};
  const bf16x8 zb8 = {0, 0, 0, 0, 0, 0, 0, 0};

  // P0: stage x -> XS [160][32] bf16 (swizzled32), zero-padded; nontemporal reads
  const float* xb = x + (size_t)b * 2700;
  for (int i = tid; i < 160 * 32; i += BDIM) {
    int r = i >> 5, c = i & 31;
    float v = (r < 135 && c < 20) ? __builtin_nontemporal_load(xb + r * 20 + c) : 0.f;
    XS[swz32(r, c)] = f2b(v);
  }

  // hoisted L1 weight fragments + biases (reused across chunks)
  const bf16x8 kw0 = frag(ws + OK1w, cb, 32, 0, lane);
  const bf16x8 kw1 = frag(ws + OK1w, cb + 16, 32, 0, lane);
  const bf16x8 vw0 = frag(ws + OV1, cb, 32, 0, lane);
  const bf16x8 vw1 = frag(ws + OV1, cb + 16, 32, 0, lane);
  const float kbb0 = kb1v[cb + l15], kbb1 = kb1v[cb + 16 + l15];
  const float vbb0 = vb1v[cb + l15], vbb1 = vb1v[cb + 16 + l15];
  __syncthreads();

  // L1 helper: H-chunk(s0) = relu(XS @ W1 + b1) -> HT2 [32][256]
  auto L1 = [&](const bf16x8& u0, const bf16x8& u1, float bb0, float bb1, int s0) {
#pragma unroll
    for (int mm = 0; mm < 2; ++mm) {
      bf16x8 a = frag32s(XS, s0 + mm * 16, lane);
      f32x4 c0 = MFMA(a, u0, zf4), c1 = MFMA(a, u1, zf4);
#pragma unroll
      for (int r = 0; r < 4; ++r) {
        HT2[swz256(mm * 16 + rs + r, cb + l15)]      = f2b(fmaxf(c0[r] + bb0, 0.f));
        HT2[swz256(mm * 16 + rs + r, cb + 16 + l15)] = f2b(fmaxf(c1[r] + bb1, 0.f));
      }
    }
  };
  // L1T helper: Hv-chunk(s0) = relu(XS @ vW1 + vb1) -> buf [256][32] TRANSPOSED
  auto L1T = [&](int s0, unsigned short* buf) {
#pragma unroll
    for (int mm = 0; mm < 2; ++mm) {
      bf16x8 a = frag32s(XS, s0 + mm * 16, lane);
      f32x4 c0 = MFMA(a, vw0, zf4), c1 = MFMA(a, vw1, zf4);
#pragma unroll
      for (int r = 0; r < 4; ++r) {
        int tok = mm * 16 + rs + r;      // 0..31 within chunk
        buf[swz32(cb + l15,      tok)] = f2b(fmaxf(c0[r] + vbb0, 0.f));
        buf[swz32(cb + 16 + l15, tok)] = f2b(fmaxf(c1[r] + vbb1, 0.f));
      }
    }
  };

  // ---------------- Q MLP (full H in arena) ----------------
  {
    bf16x8 w0 = frag(ws + OQ1, cb, 32, 0, lane);
    bf16x8 w1 = frag(ws + OQ1, cb + 16, 32, 0, lane);
    float bb0 = qb1v[cb + l15], bb1 = qb1v[cb + 16 + l15];
#pragma unroll
    for (int m = 0; m < 9; ++m) {
      bf16x8 a = frag32s(XS, m * 16, lane);
      f32x4 c0 = MFMA(a, w0, zf4);
      f32x4 c1 = MFMA(a, w1, zf4);
#pragma unroll
      for (int r = 0; r < 4; ++r) {
        Hc[swz256(m * 16 + rs + r, cb + l15)]      = f2b(fmaxf(c0[r] + bb0, 0.f));
        Hc[swz256(m * 16 + rs + r, cb + 16 + l15)] = f2b(fmaxf(c1[r] + bb1, 0.f));
      }
    }
  }
  __syncthreads();

  // ---------------- Q-L2 (reads ALL of Hc — no HT2/KVT writes in this phase) ----
  {
    f32x4 acc[9][2];
#pragma unroll
    for (int m = 0; m < 9; ++m) { acc[m][0] = zf4; acc[m][1] = zf4; }
#pragma unroll
    for (int ks = 0; ks < 8; ++ks) {
      bf16x8 g0 = frag(ws + OQ2, cb, 256, ks * 32, lane);
      bf16x8 g1 = frag(ws + OQ2, cb + 16, 256, ks * 32, lane);
#pragma unroll
      for (int m = 0; m < 9; ++m) {
        bf16x8 a = frag256s(Hc, m * 16, ks * 32, lane);
        acc[m][0] = MFMA(a, g0, acc[m][0]);
        acc[m][1] = MFMA(a, g1, acc[m][1]);
      }
    }
    float bb20 = qb2v[cb + l15], bb21 = qb2v[cb + 16 + l15];
#pragma unroll
    for (int m = 0; m < 9; ++m)
#pragma unroll
      for (int r = 0; r < 4; ++r) {
        Qs[swz256(m * 16 + rs + r, cb + l15)]      = f2b(acc[m][0][r] + bb20);
        Qs[swz256(m * 16 + rs + r, cb + 16 + l15)] = f2b(acc[m][1][r] + bb21);
      }
  }
  __syncthreads();   // Hc (H) reads complete before HT2 is overwritten

  // ---------------- K-L1(0) -> HT2 (own phase; HT2 aliases H rows ~85..117) ----
  L1(kw0, kw1, kbb0, kbb1, 0);
  __syncthreads();

  // hoisted K-L2 weight fragments: identical addresses all 5 chunks (64 VGPRs)
  bf16x8 kg[8][2];
#pragma unroll
  for (int ks = 0; ks < 8; ++ks) {
    kg[ks][0] = frag(ws + OK2w, cb, 256, ks * 32, lane);
    kg[ks][1] = frag(ws + OK2w, cb + 16, 256, ks * 32, lane);
  }

  // ---------------- K chunks: [L2] bar [L1(next)/L1T(v0) + scores] bar ----------
  for (int ch = 0; ch < 5; ++ch) {
    const int s0 = ch * 32;
    {  // K-L2 -> Ktile [32][256]
      f32x4 a2[2][2] = {{zf4, zf4}, {zf4, zf4}};
#pragma unroll
      for (int ks = 0; ks < 8; ++ks) {
#pragma unroll
        for (int mm = 0; mm < 2; ++mm) {
          bf16x8 a = frag256s(HT2, mm * 16, ks * 32, lane);
          a2[mm][0] = MFMA(a, kg[ks][0], a2[mm][0]);
          a2[mm][1] = MFMA(a, kg[ks][1], a2[mm][1]);
        }
      }
      float bb0 = kb2v[cb + l15], bb1 = kb2v[cb + 16 + l15];
#pragma unroll
      for (int mm = 0; mm < 2; ++mm)
#pragma unroll
        for (int r = 0; r < 4; ++r) {
          KVT[swz256(mm * 16 + rs + r, cb + l15)]      = f2b(a2[mm][0][r] + bb0);
          KVT[swz256(mm * 16 + rs + r, cb + 16 + l15)] = f2b(a2[mm][1][r] + bb1);
        }
    }
    __syncthreads();
    // next chunk's K-L1 into HT2, or (last) first V-L1 TRANSPOSED into VB0.
    if (ch < 4) L1(kw0, kw1, kbb0, kbb1, s0 + 32);
    else        L1T(0, VB0);
    // scores slab: S[:, s0..s0+31] = Q @ Ktile^T / 16 ; jobs j = m*2+n
#pragma unroll
    for (int rep = 0; rep < 3; ++rep) {
      int j = w + rep * 8;
      if (j < 18) {
        int m = j >> 1, n = j & 1;
        int sb = s0 + n * 16;
        if (sb < 144) {
          f32x4 sa = zf4;
#pragma unroll
          for (int ks = 0; ks < 8; ++ks) {
            bf16x8 qa = frag256s(Qs, m * 16, ks * 32, lane);
            bf16x8 kf = frag256s(KVT, n * 16, ks * 32, lane);
            sa = MFMA(qa, kf, sa);
          }
#pragma unroll
          for (int r = 0; r < 4; ++r)
            SP[(m * 16 + rs + r) * SPS + sb + l15] = f2b(sa[r] * 0.0625f);
        }
      }
    }
    __syncthreads();
  }

  // ---------------- softmax in-place (mask s>=135), denom -> RWL ----------------
#pragma unroll
  for (int pass = 0; pass < 2; ++pass) {
    int r = pass * 128 + (tid >> 2);
    if (r < 144) {
      int j = tid & 3;
      float mx = -1e30f;
      for (int s = j; s < 135; s += 4) mx = fmaxf(mx, bfu(SP[r * SPS + s]));
      mx = fmaxf(mx, __shfl_xor(mx, 1));
      mx = fmaxf(mx, __shfl_xor(mx, 2));
      float sum = 0.f;
      for (int s = j; s < 135; s += 4) {
        float p = __expf(bfu(SP[r * SPS + s]) - mx);
        SP[r * SPS + s] = f2b(p);
        sum += p;
      }
      sum += __shfl_xor(sum, 1);
      sum += __shfl_xor(sum, 2);
      if (j == 0) RWL[r] = sum;
      for (int s = 135 + j; s < 144; s += 4) SP[r * SPS + s] = 0;
    }
  }
  __syncthreads();

  // ---------------- V chunks (fused): PH += P @ Hv ; 1 barrier per chunk --------
  f32x4 ctx[9][2];
#pragma unroll
  for (int m = 0; m < 9; ++m) { ctx[m][0] = zf4; ctx[m][1] = zf4; }
#pragma unroll
  for (int ch = 0; ch < 5; ++ch) {
    const int s0 = ch * 32;
    const unsigned short* rd = (ch & 1) ? VB1 : VB0;
    unsigned short* wr = (ch & 1) ? VB0 : VB1;
    if (ch < 4) L1T(s0 + 32, wr);
    {
      bf16x8 v0 = frag32s(rd, cb, lane);
      bf16x8 v1 = frag32s(rd, cb + 16, lane);
      const bool mask = (ch == 4) && (lane >= 32);   // token slots >= 144
#pragma unroll
      for (int m = 0; m < 9; ++m) {
        bf16x8 pa = frag(SP, m * 16, SPS, s0, lane);
        if (mask) pa = zb8;
        ctx[m][0] = MFMA(pa, v0, ctx[m][0]);
        ctx[m][1] = MFMA(pa, v1, ctx[m][1]);
      }
    }
    __syncthreads();
  }

  // normalize: PHn = PH / RWL -> bf16 into Hc arena (SP/VB0/VB1 all dead)
#pragma unroll
  for (int m = 0; m < 9; ++m)
#pragma unroll
    for (int r = 0; r < 4; ++r) {
      int t = m * 16 + rs + r;
      float inv = 1.0f / RWL[t];
      Hc[swz256(t, cb + l15)]      = f2b(ctx[m][0][r] * inv);
      Hc[swz256(t, cb + 16 + l15)] = f2b(ctx[m][1][r] * inv);
    }
  __syncthreads();

  // ---------------- p-L1: hp = relu(Q @ pW1q + PHn @ G3 + pb1_adj) --------------
  {
    const float* pb1adj = (const float*)(ws + OV2);
    float pbias0 = pb1adj[cb + l15], pbias1 = pb1adj[cb + 16 + l15];
    f32x4 pacc[9][2];
#pragma unroll
    for (int m = 0; m < 9; ++m) {
      pacc[m][0] = (f32x4){pbias0, pbias0, pbias0, pbias0};
      pacc[m][1] = (f32x4){pbias1, pbias1, pbias1, pbias1};
    }
#pragma unroll
    for (int ks = 0; ks < 8; ++ks) {        // Q half (original pW1q)
      bf16x8 g0 = frag(ws + OP1, cb, 512, ks * 32, lane);
      bf16x8 g1 = frag(ws + OP1, cb + 16, 512, ks * 32, lane);
#pragma unroll
      for (int m = 0; m < 9; ++m) {
        bf16x8 a = frag256s(Qs, m * 16, ks * 32, lane);
        pacc[m][0] = MFMA(a, g0, pacc[m][0]);
        pacc[m][1] = MFMA(a, g1, pacc[m][1]);
      }
    }
#pragma unroll
    for (int ks = 0; ks < 8; ++ks) {        // PHn half (fused G3t in ctx slots)
      bf16x8 g0 = frag(ws + OP1, cb, 512, 256 + ks * 32, lane);
      bf16x8 g1 = frag(ws + OP1, cb + 16, 512, 256 + ks * 32, lane);
#pragma unroll
      for (int m = 0; m < 9; ++m) {
        bf16x8 a = frag256s(Hc, m * 16, ks * 32, lane);
        pacc[m][0] = MFMA(a, g0, pacc[m][0]);
        pacc[m][1] = MFMA(a, g1, pacc[m][1]);
      }
    }
    __syncthreads();   // Q/PHn reads done by ALL waves before hp overwrite
#pragma unroll
    for (int m = 0; m < 9; ++m)
#pragma unroll
      for (int r = 0; r < 4; ++r) {
        Hc[swz256(m * 16 + rs + r, cb + l15)]      = f2b(fmaxf(pacc[m][0][r], 0.f));
        Hc[swz256(m * 16 + rs + r, cb + 16 + l15)] = f2b(fmaxf(pacc[m][1][r], 0.f));
      }
  }
  __syncthreads();

  // ---------------- p-L2 (IDCT-folded): time = hp @ pW2M + pb2M -> Ob [144][25] --
  {
    const float* pb2M = ((const float*)(ws + OV2)) + 256;
#pragma unroll
    for (int rep = 0; rep < 3; ++rep) {
      int j = w + rep * 8;
      if (j < 18) {
        int m = j >> 1, n = j & 1;
        f32x4 oa = zf4;
#pragma unroll
        for (int ks = 0; ks < 8; ++ks) {
          bf16x8 a = frag256s(Hc, m * 16, ks * 32, lane);
          bf16x8 g = frag(ws + OP2, n * 16, 256, ks * 32, lane);
          oa = MFMA(a, g, oa);
        }
        int c = n * 16 + l15;
        if (c < 24) {
          float bb = pb2M[c];
#pragma unroll
          for (int r = 0; r < 4; ++r)
            Ob[(m * 16 + rs + r) * 25 + c] = oa[r] + bb;
        }
      }
    }
  }
  __syncthreads();

  // ---------------- transpose-copy Ob -> out (coalesced nontemporal) ----------
  for (int i = tid; i < 3240; i += BDIM) {
    int tt = i / 135, tok = i - tt * 135;
    __builtin_nontemporal_store(Ob[tok * 25 + tt], out + (size_t)b * 3240 + i);
  }
}

extern "C" void kernel_launch(void* const* d_in, const int* in_sizes, int n_in,
                              void* d_out, int out_size, void* d_ws, size_t ws_size,
                              hipStream_t stream) {
  (void)in_sizes; (void)n_in; (void)out_size;
  if (ws_size < (size_t)WTOT * 2) return;

  const float* x   = (const float*)d_in[0];
  const float* qW1 = (const float*)d_in[1];
  const float* qb1 = (const float*)d_in[2];
  const float* qW2 = (const float*)d_in[3];
  const float* qb2 = (const float*)d_in[4];
  const float* kW1 = (const float*)d_in[5];
  const float* kb1 = (const float*)d_in[6];
  const float* kW2 = (const float*)d_in[7];
  const float* kb2 = (const float*)d_in[8];
  const float* vW1 = (const float*)d_in[9];
  const float* vb1 = (const float*)d_in[10];
  const float* vW2 = (const float*)d_in[11];
  const float* vb2 = (const float*)d_in[12];
  const float* pW1 = (const float*)d_in[13];
  const float* pb1 = (const float*)d_in[14];
  const float* pW2 = (const float*)d_in[15];
  const float* pb2 = (const float*)d_in[16];
  float* out = (float*)d_out;
  unsigned short* ws = (unsigned short*)d_ws;

  prep_w<<<dim3((WTOT + 255) / 256), dim3(256), 0, stream>>>(
      qW1, qW2, kW1, kW2, vW1, vW2, pW1, pW2, ws);
  g3_prep<<<dim3(256), dim3(256), 0, stream>>>(vW2, pW1, pb1, vb2, ws);
  g5_prep<<<dim3(24), dim3(256), 0, stream>>>(pW2, pb2, ws);

  (void)hipFuncSetAttribute((const void*)motion_mfma,
                            hipFuncAttributeMaxDynamicSharedMemorySize, SMEM_BYTES);
  motion_mfma<<<dim3(2048), dim3(BDIM), SMEM_BYTES, stream>>>(
      x, qb1, qb2, kb1, kb2, vb1, vb2, ws, out);
}

// Round 17
// 539.337 us; speedup vs baseline: 1.3010x; 1.0312x over previous
//
#include <hip/hip_runtime.h>

#define BDIM 512

typedef float f32x4 __attribute__((ext_vector_type(4)));
typedef short bf16x8 __attribute__((ext_vector_type(8)));

#define MFMA(a, b, c) __builtin_amdgcn_mfma_f32_16x16x32_bf16((a), (b), (c), 0, 0, 0)

// ---- weight workspace layout (bf16 elements in d_ws) ----
constexpr int OQ1 = 0;                  // qW1t [256][32]  (k 20..31 = 0)
constexpr int OK1w = 8192;              // kW1t [256][32]
constexpr int OV1 = 16384;              // vW1t [256][32]
constexpr int OQ2 = 24576;              // qW2t [256][256]
constexpr int OK2w = 90112;             // kW2t [256][256]
constexpr int OV2 = 155648;             // vW2t region: DEAD for GEMM (V-L2 fused);
                                        // reused as f32 pb1_adj[256] (g3_prep)
constexpr int OP1 = 221184;             // [256][512]: cols 0..255 = pW1t Q-half;
                                        // cols 256..511 = G3t = (vW2 @ pW1c)^T  (g3_prep)
constexpr int OP2 = 352256;             // pW2t [32][256]  (rows 24..31 = 0)
constexpr int WTOT = 360448;            // elements (720896 bytes)

// ---- LDS layout (bytes) ---- (identical to R8/R12 champion)
// NOTE: Hc arena [144][256] spans SP+HT2+KVT (83968..157696). Any phase that
// READS Hc (Q-L2, p-L1 ctx half, p-L2) must not concurrently write HT2/KVT.
// V phase: HT2 region doubles as Hv^T buffer VB0 [256][32]; KVT as VB1.
constexpr int OFF_Q   = 0;
constexpr int OFF_XS  = 73728;
constexpr int OFF_SP  = 83968;          // 43808 bytes incl. masked-read slack
constexpr int OFF_HT2 = 127776;
constexpr int OFF_KVT = 144160;
constexpr int OFF_RWL = 160544;
constexpr int SMEM_BYTES = 161120;

constexpr int SPS = 152;                // SP row stride (elements)

__device__ __forceinline__ unsigned short f2b(float f) {
  unsigned int u = __float_as_uint(f);
  return (unsigned short)((u + 0x7fffu + ((u >> 16) & 1u)) >> 16);
}
__device__ __forceinline__ float bfu(unsigned short u) {
  return __uint_as_float(((unsigned int)u) << 16);
}

// plain fragment load: lane l -> row rb+(l&15), k-cols kb+(l>>4)*8
__device__ __forceinline__ bf16x8 frag(const unsigned short* m, int rb, int stride,
                                       int kb, int lane) {
  return *(const bf16x8*)(m + (rb + (lane & 15)) * stride + kb + ((lane >> 4) << 3));
}
// swizzled fragment loads (LDS)
__device__ __forceinline__ bf16x8 frag256s(const unsigned short* m, int rb, int kb, int lane) {
  const int row = rb + (lane & 15);
  const int c = (kb + ((lane >> 4) << 3)) ^ ((row & 7) << 3);
  return *(const bf16x8*)(m + row * 256 + c);
}
__device__ __forceinline__ bf16x8 frag32s(const unsigned short* m, int rb, int lane) {
  const int row = rb + (lane & 15);
  const int c = ((lane >> 4) << 3) ^ (((row >> 1) & 3) << 3);
  return *(const bf16x8*)(m + row * 32 + c);
}
// swizzled scalar-store index helpers (must match the frag*s formulas)
__device__ __forceinline__ int swz256(int r, int c) { return r * 256 + (c ^ ((r & 7) << 3)); }
__device__ __forceinline__ int swz32 (int r, int c) { return r * 32  + (c ^ (((r >> 1) & 3) << 3)); }

// ---------------- weight prep: f32 -> bf16, transposed, padded ----------------
__global__ void prep_w(const float* __restrict__ qW1, const float* __restrict__ qW2,
                       const float* __restrict__ kW1, const float* __restrict__ kW2,
                       const float* __restrict__ vW1, const float* __restrict__ vW2,
                       const float* __restrict__ pW1, const float* __restrict__ pW2,
                       unsigned short* __restrict__ ws) {
  int i = blockIdx.x * 256 + threadIdx.x;
  if (i >= WTOT) return;
  float v = 0.f;
  if (i < OQ2) {
    int sel = i >> 13, r = i & 8191;
    int o = r >> 5, k = r & 31;
    const float* W = (sel == 0) ? qW1 : (sel == 1) ? kW1 : vW1;
    if (k < 20) v = W[k * 256 + o];
  } else if (i < OP1) {
    int r = i - OQ2;
    int sel = r >> 16, q = r & 65535;
    int o = q >> 8, k = q & 255;
    const float* W = (sel == 0) ? qW2 : (sel == 1) ? kW2 : vW2;
    v = W[k * 256 + o];
  } else if (i < OP2) {
    int r = i - OP1;
    int o = r >> 9, f = r & 511;
    v = pW1[f * 256 + o];                // ctx half overwritten by g3_prep later
  } else {
    int r = i - OP2;
    int o = r >> 8, k = r & 255;
    if (o < 24) v = pW2[k * 24 + o];
  }
  ws[i] = f2b(v);
}

// ---------------- fused-weight prep: G3t = (vW2 @ pW1c)^T; pb1_adj ----------------
// block = output column o (256 blocks); thread = c (256)
__global__ void g3_prep(const float* __restrict__ vW2, const float* __restrict__ pW1,
                        const float* __restrict__ pb1, const float* __restrict__ vb2,
                        unsigned short* __restrict__ ws) {
  __shared__ float col[256];             // pW1[256+h][o], h = 0..255
  __shared__ float red[256];
  const int o = blockIdx.x, c = threadIdx.x;
  col[c] = pW1[(256 + c) * 256 + o];
  __syncthreads();
  float acc = 0.f;
#pragma unroll 4
  for (int h = 0; h < 256; ++h) acc += vW2[c * 256 + h] * col[h];
  ws[OP1 + o * 512 + 256 + c] = f2b(acc);          // G3t[o][c] into OP1 ctx slot
  red[c] = vb2[c] * col[c];
  __syncthreads();
  for (int st = 128; st > 0; st >>= 1) {
    if (c < st) red[c] += red[c + st];
    __syncthreads();
  }
  if (c == 0) ((float*)(ws + OV2))[o] = pb1[o] + red[0];   // pb1_adj[o]
}

// ---------------- fused main kernel: 1 block = 1 batch, 8 waves ----------------
__global__ __launch_bounds__(BDIM) __attribute__((amdgpu_waves_per_eu(2, 2)))
void motion_mfma(const float* __restrict__ x,
                 const float* __restrict__ qb1v, const float* __restrict__ qb2v,
                 const float* __restrict__ kb1v, const float* __restrict__ kb2v,
                 const float* __restrict__ vb1v, const float* __restrict__ vb2v,
                 const float* __restrict__ pb1v, const float* __restrict__ pb2v,
                 const unsigned short* __restrict__ ws,
                 float* __restrict__ out) {
  extern __shared__ char smem[];
  unsigned short* Qs  = (unsigned short*)(smem + OFF_Q);
  unsigned short* XS  = (unsigned short*)(smem + OFF_XS);
  unsigned short* SP  = (unsigned short*)(smem + OFF_SP);
  unsigned short* Hc  = (unsigned short*)(smem + OFF_SP);   // H / PHn / hp arena
  unsigned short* HT2 = (unsigned short*)(smem + OFF_HT2);
  unsigned short* KVT = (unsigned short*)(smem + OFF_KVT);
  unsigned short* VB0 = (unsigned short*)(smem + OFF_HT2);  // Hv^T buf A [256][32]
  unsigned short* VB1 = (unsigned short*)(smem + OFF_KVT);  // Hv^T buf B [256][32]
  float* RWL = (float*)(smem + OFF_RWL);
  float* Ob  = (float*)(smem + 0);
  float* MT  = (float*)(smem + 14400);

  const int tid = threadIdx.x, lane = tid & 63, w = tid >> 6;
  const int l15 = lane & 15, rs = ((lane >> 4) << 2);
  const int cb = w * 32;               // wave's two 16-col n-tiles
  const int b = blockIdx.x;
  const f32x4 zf4 = {0.f, 0.f, 0.f, 0.f};
  const bf16x8 zb8 = {0, 0, 0, 0, 0, 0, 0, 0};

  // P0: stage x -> XS [160][32] bf16 (swizzled32), zero-padded; nontemporal reads
  const float* xb = x + (size_t)b * 2700;
  for (int i = tid; i < 160 * 32; i += BDIM) {
    int r = i >> 5, c = i & 31;
    float v = (r < 135 && c < 20) ? __builtin_nontemporal_load(xb + r * 20 + c) : 0.f;
    XS[swz32(r, c)] = f2b(v);
  }

  // hoisted L1 weight fragments + biases (reused across chunks)
  const bf16x8 kw0 = frag(ws + OK1w, cb, 32, 0, lane);
  const bf16x8 kw1 = frag(ws + OK1w, cb + 16, 32, 0, lane);
  const bf16x8 vw0 = frag(ws + OV1, cb, 32, 0, lane);
  const bf16x8 vw1 = frag(ws + OV1, cb + 16, 32, 0, lane);
  const float kbb0 = kb1v[cb + l15], kbb1 = kb1v[cb + 16 + l15];
  const float vbb0 = vb1v[cb + l15], vbb1 = vb1v[cb + 16 + l15];
  __syncthreads();

  // L1 helper: H-chunk(s0) = relu(XS @ W1 + b1) -> HT2 [32][256]
  auto L1 = [&](const bf16x8& u0, const bf16x8& u1, float bb0, float bb1, int s0) {
#pragma unroll
    for (int mm = 0; mm < 2; ++mm) {
      bf16x8 a = frag32s(XS, s0 + mm * 16, lane);
      f32x4 c0 = MFMA(a, u0, zf4), c1 = MFMA(a, u1, zf4);
#pragma unroll
      for (int r = 0; r < 4; ++r) {
        HT2[swz256(mm * 16 + rs + r, cb + l15)]      = f2b(fmaxf(c0[r] + bb0, 0.f));
        HT2[swz256(mm * 16 + rs + r, cb + 16 + l15)] = f2b(fmaxf(c1[r] + bb1, 0.f));
      }
    }
  };
  // L1T helper: Hv-chunk(s0) = relu(XS @ vW1 + vb1) -> buf [256][32] TRANSPOSED
  auto L1T = [&](int s0, unsigned short* buf) {
#pragma unroll
    for (int mm = 0; mm < 2; ++mm) {
      bf16x8 a = frag32s(XS, s0 + mm * 16, lane);
      f32x4 c0 = MFMA(a, vw0, zf4), c1 = MFMA(a, vw1, zf4);
#pragma unroll
      for (int r = 0; r < 4; ++r) {
        int tok = mm * 16 + rs + r;      // 0..31 within chunk
        buf[swz32(cb + l15,      tok)] = f2b(fmaxf(c0[r] + vbb0, 0.f));
        buf[swz32(cb + 16 + l15, tok)] = f2b(fmaxf(c1[r] + vbb1, 0.f));
      }
    }
  };

  // ---------------- Q MLP (full H in arena) ----------------
  {
    bf16x8 w0 = frag(ws + OQ1, cb, 32, 0, lane);
    bf16x8 w1 = frag(ws + OQ1, cb + 16, 32, 0, lane);
    float bb0 = qb1v[cb + l15], bb1 = qb1v[cb + 16 + l15];
#pragma unroll
    for (int m = 0; m < 9; ++m) {
      bf16x8 a = frag32s(XS, m * 16, lane);
      f32x4 c0 = MFMA(a, w0, zf4);
      f32x4 c1 = MFMA(a, w1, zf4);
#pragma unroll
      for (int r = 0; r < 4; ++r) {
        Hc[swz256(m * 16 + rs + r, cb + l15)]      = f2b(fmaxf(c0[r] + bb0, 0.f));
        Hc[swz256(m * 16 + rs + r, cb + 16 + l15)] = f2b(fmaxf(c1[r] + bb1, 0.f));
      }
    }
  }
  __syncthreads();

  // ---------------- Q-L2 (reads ALL of Hc — no HT2/KVT writes in this phase) ----
  {
    f32x4 acc[9][2];
#pragma unroll
    for (int m = 0; m < 9; ++m) { acc[m][0] = zf4; acc[m][1] = zf4; }
#pragma unroll
    for (int ks = 0; ks < 8; ++ks) {
      bf16x8 g0 = frag(ws + OQ2, cb, 256, ks * 32, lane);
      bf16x8 g1 = frag(ws + OQ2, cb + 16, 256, ks * 32, lane);
#pragma unroll
      for (int m = 0; m < 9; ++m) {
        bf16x8 a = frag256s(Hc, m * 16, ks * 32, lane);
        acc[m][0] = MFMA(a, g0, acc[m][0]);
        acc[m][1] = MFMA(a, g1, acc[m][1]);
      }
    }
    float bb20 = qb2v[cb + l15], bb21 = qb2v[cb + 16 + l15];
#pragma unroll
    for (int m = 0; m < 9; ++m)
#pragma unroll
      for (int r = 0; r < 4; ++r) {
        Qs[swz256(m * 16 + rs + r, cb + l15)]      = f2b(acc[m][0][r] + bb20);
        Qs[swz256(m * 16 + rs + r, cb + 16 + l15)] = f2b(acc[m][1][r] + bb21);
      }
  }
  __syncthreads();   // Hc (H) reads complete before HT2 is overwritten

  // ---------------- K-L1(0) -> HT2 (own phase; HT2 aliases H rows ~85..117) ----
  L1(kw0, kw1, kbb0, kbb1, 0);
  __syncthreads();

  // hoisted K-L2 weight fragments: identical addresses all 5 chunks (64 VGPRs)
  bf16x8 kg[8][2];
#pragma unroll
  for (int ks = 0; ks < 8; ++ks) {
    kg[ks][0] = frag(ws + OK2w, cb, 256, ks * 32, lane);
    kg[ks][1] = frag(ws + OK2w, cb + 16, 256, ks * 32, lane);
  }

  // ---------------- K chunks: [L2] bar [L1(next)/L1T(v0) + scores] bar ----------
  for (int ch = 0; ch < 5; ++ch) {
    const int s0 = ch * 32;
    {  // K-L2 -> Ktile [32][256]
      f32x4 a2[2][2] = {{zf4, zf4}, {zf4, zf4}};
#pragma unroll
      for (int ks = 0; ks < 8; ++ks) {
#pragma unroll
        for (int mm = 0; mm < 2; ++mm) {
          bf16x8 a = frag256s(HT2, mm * 16, ks * 32, lane);
          a2[mm][0] = MFMA(a, kg[ks][0], a2[mm][0]);
          a2[mm][1] = MFMA(a, kg[ks][1], a2[mm][1]);
        }
      }
      float bb0 = kb2v[cb + l15], bb1 = kb2v[cb + 16 + l15];
#pragma unroll
      for (int mm = 0; mm < 2; ++mm)
#pragma unroll
        for (int r = 0; r < 4; ++r) {
          KVT[swz256(mm * 16 + rs + r, cb + l15)]      = f2b(a2[mm][0][r] + bb0);
          KVT[swz256(mm * 16 + rs + r, cb + 16 + l15)] = f2b(a2[mm][1][r] + bb1);
        }
    }
    __syncthreads();
    // next chunk's K-L1 into HT2, or (last) first V-L1 TRANSPOSED into VB0.
    // VB0 == HT2 region; scores below reads KVT/Qs, writes SP — disjoint.
    if (ch < 4) L1(kw0, kw1, kbb0, kbb1, s0 + 32);
    else        L1T(0, VB0);
    // scores slab: S[:, s0..s0+31] = Q @ Ktile^T / 16 ; jobs j = m*2+n
#pragma unroll
    for (int rep = 0; rep < 3; ++rep) {
      int j = w + rep * 8;
      if (j < 18) {
        int m = j >> 1, n = j & 1;
        int sb = s0 + n * 16;
        if (sb < 144) {
          f32x4 sa = zf4;
#pragma unroll
          for (int ks = 0; ks < 8; ++ks) {
            bf16x8 qa = frag256s(Qs, m * 16, ks * 32, lane);
            bf16x8 kf = frag256s(KVT, n * 16, ks * 32, lane);
            sa = MFMA(qa, kf, sa);
          }
#pragma unroll
          for (int r = 0; r < 4; ++r)
            SP[(m * 16 + rs + r) * SPS + sb + l15] = f2b(sa[r] * 0.0625f);
        }
      }
    }
    __syncthreads();
  }

  // ---------------- softmax in-place (mask s>=135), denom -> RWL ----------------
#pragma unroll
  for (int pass = 0; pass < 2; ++pass) {
    int r = pass * 128 + (tid >> 2);
    if (r < 144) {
      int j = tid & 3;
      float mx = -1e30f;
      for (int s = j; s < 135; s += 4) mx = fmaxf(mx, bfu(SP[r * SPS + s]));
      mx = fmaxf(mx, __shfl_xor(mx, 1));
      mx = fmaxf(mx, __shfl_xor(mx, 2));
      float sum = 0.f;
      for (int s = j; s < 135; s += 4) {
        float p = __expf(bfu(SP[r * SPS + s]) - mx);
        SP[r * SPS + s] = f2b(p);
        sum += p;
      }
      sum += __shfl_xor(sum, 1);
      sum += __shfl_xor(sum, 2);
      if (j == 0) RWL[r] = sum;
      for (int s = 135 + j; s < 144; s += 4) SP[r * SPS + s] = 0;
    }
  }
  __syncthreads();

  // ---------------- V chunks (fused): PH += P @ Hv ; 1 barrier per chunk --------
  // fully unrolled: rd/wr compile-time pointers (R14-validated form)
  f32x4 ctx[9][2];
#pragma unroll
  for (int m = 0; m < 9; ++m) { ctx[m][0] = zf4; ctx[m][1] = zf4; }
#pragma unroll
  for (int ch = 0; ch < 5; ++ch) {
    const int s0 = ch * 32;
    const unsigned short* rd = (ch & 1) ? VB1 : VB0;
    unsigned short* wr = (ch & 1) ? VB0 : VB1;
    if (ch < 4) L1T(s0 + 32, wr);
    {
      bf16x8 v0 = frag32s(rd, cb, lane);
      bf16x8 v1 = frag32s(rd, cb + 16, lane);
      const bool mask = (ch == 4) && (lane >= 32);   // token slots >= 144
#pragma unroll
      for (int m = 0; m < 9; ++m) {
        bf16x8 pa = frag(SP, m * 16, SPS, s0, lane);
        if (mask) pa = zb8;
        ctx[m][0] = MFMA(pa, v0, ctx[m][0]);
        ctx[m][1] = MFMA(pa, v1, ctx[m][1]);
      }
    }
    __syncthreads();
  }

  // normalize: PHn = PH / RWL -> bf16 into Hc arena (SP/VB0/VB1 all dead)
#pragma unroll
  for (int m = 0; m < 9; ++m)
#pragma unroll
    for (int r = 0; r < 4; ++r) {
      int t = m * 16 + rs + r;
      float inv = 1.0f / RWL[t];
      Hc[swz256(t, cb + l15)]      = f2b(ctx[m][0][r] * inv);
      Hc[swz256(t, cb + 16 + l15)] = f2b(ctx[m][1][r] * inv);
    }
  __syncthreads();

  // ---------------- p-L1: hp = relu(Q @ pW1q + PHn @ G3 + pb1_adj) --------------
  {
    const float* pb1adj = (const float*)(ws + OV2);
    float pbias0 = pb1adj[cb + l15], pbias1 = pb1adj[cb + 16 + l15];
    f32x4 pacc[9][2];
#pragma unroll
    for (int m = 0; m < 9; ++m) {
      pacc[m][0] = (f32x4){pbias0, pbias0, pbias0, pbias0};
      pacc[m][1] = (f32x4){pbias1, pbias1, pbias1, pbias1};
    }
#pragma unroll
    for (int ks = 0; ks < 8; ++ks) {        // Q half (original pW1q)
      bf16x8 g0 = frag(ws + OP1, cb, 512, ks * 32, lane);
      bf16x8 g1 = frag(ws + OP1, cb + 16, 512, ks * 32, lane);
#pragma unroll
      for (int m = 0; m < 9; ++m) {
        bf16x8 a = frag256s(Qs, m * 16, ks * 32, lane);
        pacc[m][0] = MFMA(a, g0, pacc[m][0]);
        pacc[m][1] = MFMA(a, g1, pacc[m][1]);
      }
    }
#pragma unroll
    for (int ks = 0; ks < 8; ++ks) {        // PHn half (fused G3t in ctx slots)
      bf16x8 g0 = frag(ws + OP1, cb, 512, 256 + ks * 32, lane);
      bf16x8 g1 = frag(ws + OP1, cb + 16, 512, 256 + ks * 32, lane);
#pragma unroll
      for (int m = 0; m < 9; ++m) {
        bf16x8 a = frag256s(Hc, m * 16, ks * 32, lane);
        pacc[m][0] = MFMA(a, g0, pacc[m][0]);
        pacc[m][1] = MFMA(a, g1, pacc[m][1]);
      }
    }
    __syncthreads();   // Q/PHn reads done by ALL waves before hp/MT overwrite
#pragma unroll
    for (int m = 0; m < 9; ++m)
#pragma unroll
      for (int r = 0; r < 4; ++r) {
        Hc[swz256(m * 16 + rs + r, cb + l15)]      = f2b(fmaxf(pacc[m][0][r], 0.f));
        Hc[swz256(m * 16 + rs + r, cb + 16 + l15)] = f2b(fmaxf(pacc[m][1][r], 0.f));
      }
  }
  // IDCT basis into MT (Q region is dead)
  for (int i = tid; i < 576; i += BDIM) {
    int kk = i / 24, t = i - kk * 24;
    float c = (kk == 0) ? 0.20412414523193150f : 0.28867513459481287f;
    MT[i] = c * cosf(0.065449846949787352f * (float)(kk * (2 * t + 1)));
  }
  __syncthreads();

  // ---------------- p-L2: o = hp @ pW2 + pb2 -> Ob [144][25] f32 ----------------
#pragma unroll
  for (int rep = 0; rep < 3; ++rep) {
    int j = w + rep * 8;
    if (j < 18) {
      int m = j >> 1, n = j & 1;
      f32x4 oa = zf4;
#pragma unroll
      for (int ks = 0; ks < 8; ++ks) {
        bf16x8 a = frag256s(Hc, m * 16, ks * 32, lane);
        bf16x8 g = frag(ws + OP2, n * 16, 256, ks * 32, lane);
        oa = MFMA(a, g, oa);
      }
      int c = n * 16 + l15;
      if (c < 24) {
        float bb = pb2v[c];
#pragma unroll
        for (int r = 0; r < 4; ++r)
          Ob[(m * 16 + rs + r) * 25 + c] = oa[r] + bb;
      }
    }
  }
  __syncthreads();

  // ---------------- IDCT + coalesced nontemporal store ----------------
  for (int i = tid; i < 3240; i += BDIM) {
    int tt = i / 135, tok = i - tt * 135;
    float a = 0.f;
#pragma unroll
    for (int k = 0; k < 24; ++k)
      a = fmaf(Ob[tok * 25 + k], MT[k * 24 + tt], a);
    __builtin_nontemporal_store(a, out + (size_t)b * 3240 + i);
  }
}

extern "C" void kernel_launch(void* const* d_in, const int* in_sizes, int n_in,
                              void* d_out, int out_size, void* d_ws, size_t ws_size,
                              hipStream_t stream) {
  (void)in_sizes; (void)n_in; (void)out_size;
  if (ws_size < (size_t)WTOT * 2) return;

  const float* x   = (const float*)d_in[0];
  const float* qW1 = (const float*)d_in[1];
  const float* qb1 = (const float*)d_in[2];
  const float* qW2 = (const float*)d_in[3];
  const float* qb2 = (const float*)d_in[4];
  const float* kW1 = (const float*)d_in[5];
  const float* kb1 = (const float*)d_in[6];
  const float* kW2 = (const float*)d_in[7];
  const float* kb2 = (const float*)d_in[8];
  const float* vW1 = (const float*)d_in[9];
  const float* vb1 = (const float*)d_in[10];
  const float* vW2 = (const float*)d_in[11];
  const float* vb2 = (const float*)d_in[12];
  const float* pW1 = (const float*)d_in[13];
  const float* pb1 = (const float*)d_in[14];
  const float* pW2 = (const float*)d_in[15];
  const float* pb2 = (const float*)d_in[16];
  float* out = (float*)d_out;
  unsigned short* ws = (unsigned short*)d_ws;

  prep_w<<<dim3((WTOT + 255) / 256), dim3(256), 0, stream>>>(
      qW1, qW2, kW1, kW2, vW1, vW2, pW1, pW2, ws);
  g3_prep<<<dim3(256), dim3(256), 0, stream>>>(vW2, pW1, pb1, vb2, ws);

  (void)hipFuncSetAttribute((const void*)motion_mfma,
                            hipFuncAttributeMaxDynamicSharedMemorySize, SMEM_BYTES);
  motion_mfma<<<dim3(2048), dim3(BDIM), SMEM_BYTES, stream>>>(
      x, qb1, qb2, kb1, kb2, vb1, vb2, pb1, pb2, ws, out);
}